// Round 8
// baseline (157.572 us; speedup 1.0000x reference)
//
#include <hip/hip_runtime.h>
#include <math.h>

#define HW 65536
#define DD 160
#define NB 2
#define DCH 80
#define NSL (DCH + 6)   // 86 marched slices per chunk incl. halo
#define NCH 2
#define TW 32
#define TH 16
#define PH 23           // h-pitch in f32x2 units (odd -> 2-way LDS, free)

#define SSIM_C1 1e-4f
#define SSIM_C2 9e-4f

typedef float f32x2 __attribute__((ext_vector_type(2)));
typedef float f32x4 __attribute__((ext_vector_type(4)));

struct Gw { float g[7]; };

static __device__ __forceinline__ f32x2 s2(float v) { f32x2 r; r.x = v; r.y = v; return r; }

// Fused SSIM3D v8: packed-fp32 fields; DCH=80 (7.5% halo); interior blocks
// load the 10-wide W window as 3 aligned float4 (window start = 1 mod 4),
// edge blocks use clamped scalar loads masked at load time.
__global__ __launch_bounds__(256, 2) void k_fused(
    const float* __restrict__ img1, const float* __restrict__ img2,
    Gw gw, float* __restrict__ partials)
{
    __shared__ f32x2 pA[2][TW][PH];   // (conv_w x, conv_w y)
    __shared__ f32x2 pB[2][TW][PH];   // (conv_w xx, conv_w yy)
    __shared__ float pC[2][TW][PH];   // conv_w xy
    __shared__ float red[256];

    const int tid = threadIdx.x;
    const int nb = blockIdx.z >> 1;
    const int o0 = (blockIdx.z & 1) * DCH;
    const int h0 = blockIdx.y * TH;
    const int w0 = blockIdx.x * TW;
    const float* i1 = img1 + (size_t)nb * DD * HW;
    const float* i2 = img2 + (size_t)nb * DD * HW;
    const bool fastb = (blockIdx.x >= 1) && (blockIdx.x <= 6) &&
                       (blockIdx.y >= 1) && (blockIdx.y <= 14);

    // ---- W-thread geometry (tid < 176): row hh (0..21), 4 outputs at wb ----
    const bool wth = (tid < 176);
    const int hh = tid >> 3;
    const int wb = (tid & 7) * 4;
    const int gh = h0 - 3 + hh;
    const int gwb = w0 - 3 + wb;       // == 1 (mod 4)
    const bool ghv = wth && ((unsigned)gh < 256u);
    const int ghc = gh < 0 ? 0 : (gh > 255 ? 255 : gh);
    const int gbase = gh * 256 + (gwb - 1);   // 16B-aligned (fast path only)
    int coff[10];
    unsigned wbits = 0;
#pragma unroll
    for (int i = 0; i < 10; ++i) {
        int gwi = gwb + i;
        int gc = gwi < 0 ? 0 : (gwi > 255 ? 255 : gwi);
        coff[i] = ghc * 256 + gc;                 // always-in-bounds address
        if (ghv && gwi == gc) wbits |= (1u << i); // zero-pad mask bit
    }

    // ---- H/D geometry: all 256 threads, 2 output rows each ----
    const int wcol = tid & 31;
    const int hb = (tid >> 5) * 2;   // 0..14

    f32x2 ringA[2][7] = {};
    f32x2 ringB[2][7] = {};
    float ringC[2][7] = {};
    float lsum = 0.f;
    f32x2 cxy[10];

    // slice loader: fills cxy (x from img1, y from img2), zero-padded
    auto LOAD = [&](int s) {
        const float* p1 = i1 + (size_t)s * HW;
        const float* p2 = i2 + (size_t)s * HW;
        if (fastb) {
            const f32x4 a0 = *(const f32x4*)(p1 + gbase);
            const f32x4 a1 = *(const f32x4*)(p1 + gbase + 4);
            const f32x4 a2 = *(const f32x4*)(p1 + gbase + 8);
            const f32x4 b0 = *(const f32x4*)(p2 + gbase);
            const f32x4 b1 = *(const f32x4*)(p2 + gbase + 4);
            const f32x4 b2 = *(const f32x4*)(p2 + gbase + 8);
            cxy[0].x = a0.y; cxy[1].x = a0.z; cxy[2].x = a0.w; cxy[3].x = a1.x;
            cxy[4].x = a1.y; cxy[5].x = a1.z; cxy[6].x = a1.w; cxy[7].x = a2.x;
            cxy[8].x = a2.y; cxy[9].x = a2.z;
            cxy[0].y = b0.y; cxy[1].y = b0.z; cxy[2].y = b0.w; cxy[3].y = b1.x;
            cxy[4].y = b1.y; cxy[5].y = b1.z; cxy[6].y = b1.w; cxy[7].y = b2.x;
            cxy[8].y = b2.y; cxy[9].y = b2.z;
        } else {
#pragma unroll
            for (int i = 0; i < 10; ++i) {
                const float vx = p1[coff[i]];
                const float vy = p2[coff[i]];
                const bool ok = (wbits >> i) & 1u;
                cxy[i].x = ok ? vx : 0.f;
                cxy[i].y = ok ? vy : 0.f;
            }
        }
    };

    // prologue: load slice r=0 (s = o0-3)
    {
        const int s0 = o0 - 3;
        if (s0 >= 0 && wth) LOAD(s0);
    }

    for (int t = 0; t < 13; ++t) {
#pragma unroll
        for (int p = 0; p < 7; ++p) {
            const int r = 7 * t + p;
            if (r <= NSL) {
                const int scur = o0 - 3 + r;
                const bool wv = (r < NSL) && (scur >= 0) && (scur < DD);
                const int snx = scur + 1;
                const bool pfv = (r + 1 < NSL) && (snx >= 0) && (snx < DD);

                // 1) W-pass from registers -> planes[r&1]
                if (wv && wth) {
                    f32x2 aA[4] = {};
                    f32x2 aB[4] = {};
                    float aC[4] = {};
#pragma unroll
                    for (int i = 0; i < 10; ++i) {
                        const f32x2 xi2 = cxy[i];
                        const f32x2 xx2 = xi2 * xi2;      // v_pk_mul_f32
                        const float xy = xi2.x * xi2.y;
#pragma unroll
                        for (int o = 0; o < 4; ++o) {
                            const int k = i - o;
                            if (k >= 0 && k < 7) {
                                const float gk = gw.g[k];
                                aA[o] += s2(gk) * xi2;    // v_pk_fma_f32
                                aB[o] += s2(gk) * xx2;
                                aC[o] += gk * xy;
                            }
                        }
                    }
                    const int buf = r & 1;
#pragma unroll
                    for (int o = 0; o < 4; ++o) {
                        pA[buf][wb + o][hh] = aA[o];
                        pB[buf][wb + o][hh] = aB[o];
                        pC[buf][wb + o][hh] = aC[o];
                    }
                }

                // 2) prefetch next slice into cxy (consumed next iteration)
                if (pfv && wth) LOAD(snx);

                // 3) H-pass + D-ring + SSIM for slice rp = r-1 (other buffer)
                if (r >= 1) {
                    const int rp = r - 1;
                    const int sp = o0 - 3 + rp;
                    const int pi = (p + 6) % 7;   // == rp % 7, compile-time
                    if (sp >= 0 && sp < DD) {
                        const int buf = rp & 1;
                        f32x2 vA[8], vB[8];
                        float vC[8];
#pragma unroll
                        for (int i = 0; i < 8; ++i) {
                            vA[i] = pA[buf][wcol][hb + i];
                            vB[i] = pB[buf][wcol][hb + i];
                            vC[i] = pC[buf][wcol][hb + i];
                        }
#pragma unroll
                        for (int o = 0; o < 2; ++o) {
                            f32x2 aA = s2(0.f), aB = s2(0.f);
                            float aC = 0.f;
#pragma unroll
                            for (int k = 0; k < 7; ++k) {
                                const float gk = gw.g[k];
                                aA += s2(gk) * vA[o + k];
                                aB += s2(gk) * vB[o + k];
                                aC += gk * vC[o + k];
                            }
                            ringA[o][pi] = aA;
                            ringB[o][pi] = aB;
                            ringC[o][pi] = aC;
                        }
                    } else {
#pragma unroll
                        for (int o = 0; o < 2; ++o) {
                            ringA[o][pi] = s2(0.f);
                            ringB[o][pi] = s2(0.f);
                            ringC[o][pi] = 0.f;
                        }
                    }
                    if (r >= 7) {
                        f32x2 CA[2], CB[2];
                        float CC[2];
#pragma unroll
                        for (int o = 0; o < 2; ++o) {
                            f32x2 cA = s2(0.f), cB = s2(0.f);
                            float cC = 0.f;
#pragma unroll
                            for (int k = 0; k < 7; ++k) {
                                const float gk = gw.g[k];
                                const int pp = (pi + 1 + k) % 7;
                                cA += s2(gk) * ringA[o][pp];
                                cB += s2(gk) * ringB[o][pp];
                                cC += gk * ringC[o][pp];
                            }
                            CA[o] = cA; CB[o] = cB; CC[o] = cC;
                        }
                        // packed SSIM over the two h-outputs (repack is free)
                        f32x2 mu1, mu2, E11, E22, E12;
                        mu1.x = CA[0].x; mu1.y = CA[1].x;
                        mu2.x = CA[0].y; mu2.y = CA[1].y;
                        E11.x = CB[0].x; E11.y = CB[1].x;
                        E22.x = CB[0].y; E22.y = CB[1].y;
                        E12.x = CC[0];   E12.y = CC[1];
                        const f32x2 mu1s = mu1 * mu1;
                        const f32x2 mu2s = mu2 * mu2;
                        const f32x2 m12 = mu1 * mu2;
                        const f32x2 sg1 = E11 - mu1s;
                        const f32x2 sg2 = E22 - mu2s;
                        const f32x2 s12 = E12 - m12;
                        const f32x2 num = (s2(2.f) * m12 + s2(SSIM_C1)) *
                                          (s2(2.f) * s12 + s2(SSIM_C2));
                        const f32x2 den = (mu1s + mu2s + s2(SSIM_C1)) *
                                          (sg1 + sg2 + s2(SSIM_C2));
                        lsum += num.x * __builtin_amdgcn_rcpf(den.x)
                              + num.y * __builtin_amdgcn_rcpf(den.y);
                    }
                }
                __syncthreads();
            }
        }
    }

    // deterministic block reduction
    red[tid] = lsum;
    __syncthreads();
    for (int off = 128; off > 0; off >>= 1) {
        if (tid < off) red[tid] += red[tid + off];
        __syncthreads();
    }
    if (tid == 0)
        partials[(blockIdx.z * gridDim.y + blockIdx.y) * gridDim.x + blockIdx.x] = red[0];
}

__global__ __launch_bounds__(256) void k_final(
    const float* __restrict__ partials, int n, float scale, float* __restrict__ out)
{
    __shared__ float red[256];
    float s = 0.f;
    for (int i = threadIdx.x; i < n; i += 256) s += partials[i];
    red[threadIdx.x] = s;
    __syncthreads();
    for (int off = 128; off > 0; off >>= 1) {
        if (threadIdx.x < off) red[threadIdx.x] += red[threadIdx.x + off];
        __syncthreads();
    }
    if (threadIdx.x == 0) out[0] = red[0] * scale;
}

extern "C" void kernel_launch(void* const* d_in, const int* in_sizes, int n_in,
                              void* d_out, int out_size, void* d_ws, size_t ws_size,
                              hipStream_t stream)
{
    const float* img1 = (const float*)d_in[0];
    const float* img2 = (const float*)d_in[1];
    float* out = (float*)d_out;
    float* partials = (float*)d_ws;

    Gw gw;
    {
        double gs[7], sum = 0.0;
        for (int i = 0; i < 7; ++i) { double x = i - 3; gs[i] = exp(-x * x / 4.5); sum += gs[i]; }
        for (int i = 0; i < 7; ++i) gw.g[i] = (float)(gs[i] / sum);
    }

    dim3 grid(256 / TW, 256 / TH, NB * NCH);   // 8 x 16 x 4 = 512 blocks
    k_fused<<<grid, dim3(256), 0, stream>>>(img1, img2, gw, partials);
    k_final<<<dim3(1), dim3(256), 0, stream>>>(
        partials, (256 / TW) * (256 / TH) * NB * NCH, (float)(1.0 / 20971520.0), out);
}